// Round 3
// baseline (221.075 us; speedup 1.0000x reference)
//
#include <hip/hip_runtime.h>
#include <hip/hip_bf16.h>

// B=8, S=1024, D=1024, H=16, HD=64, R=8, SCALING=2.0, DFF=4096, DC=512, NC=3.
// Output depends only on h[:,0]. Key identity: attention at query 0 never needs
// K or V materialized:
//   score[b,h,k] = sum_c qh[b,h,c] * h[b,k,c],  qh = per-head pullback of q0 through WkE
//   ctx[b,n]     = sum_c pv[b,head(n),c] * WvE[n,c],  pv[b,h,c] = sum_k p[b,h,k] h[b,k,c]
// This removes both full-size GEMMs (was 45us) and all K/V traffic.

typedef float f32x4 __attribute__((ext_vector_type(4)));

__device__ __forceinline__ float bf2f(unsigned short u) {
  union { unsigned int i; float f; } v; v.i = ((unsigned int)u) << 16; return v.f;
}
__device__ __forceinline__ float blo(unsigned int u) {
  union { unsigned int i; float f; } v; v.i = u << 16; return v.f;
}
__device__ __forceinline__ float bhi(unsigned int u) {
  union { unsigned int i; float f; } v; v.i = u & 0xffff0000u; return v.f;
}
__device__ __forceinline__ unsigned short f2bf(float f) {
  union { float f; unsigned int i; } v; v.f = f;
  unsigned int u = v.i;
  u += 0x7FFFu + ((u >> 16) & 1u);
  return (unsigned short)(u >> 16);
}
__device__ __forceinline__ float gelu_exact(float x) {
  return 0.5f * x * (1.0f + erff(x * 0.70710678118654752440f));
}

// ---------------- LN1 fused: blocks 0..8191 -> h bf16; blocks 8192..8199 -> x0 fp32 (s=0 rows)
__global__ __launch_bounds__(256) void ln_fused(
    const float* __restrict__ x, const float* __restrict__ g,
    const float* __restrict__ b, unsigned short* __restrict__ hbf,
    float* __restrict__ x0) {
  int blk = blockIdx.x;
  int f32out = (blk >= 8192);
  const float* xr = f32out ? (x + (size_t)(blk - 8192) * 1048576)
                           : (x + (size_t)blk * 1024);
  int t = threadIdx.x;
  float4 v = ((const float4*)xr)[t];
  float s  = v.x + v.y + v.z + v.w;
  float sq = v.x * v.x + v.y * v.y + v.z * v.z + v.w * v.w;
#pragma unroll
  for (int o = 32; o; o >>= 1) { s += __shfl_down(s, o); sq += __shfl_down(sq, o); }
  __shared__ float rs_[4], rq_[4], stat[2];
  int w = t >> 6, l = t & 63;
  if (l == 0) { rs_[w] = s; rq_[w] = sq; }
  __syncthreads();
  if (t == 0) {
    float S = rs_[0] + rs_[1] + rs_[2] + rs_[3];
    float Q = rq_[0] + rq_[1] + rq_[2] + rq_[3];
    float mu = S * (1.0f / 1024.0f);
    float var = Q * (1.0f / 1024.0f) - mu * mu;
    stat[0] = mu; stat[1] = rsqrtf(var + 1e-5f);
  }
  __syncthreads();
  float mu = stat[0], rstd = stat[1];
  float4 gg = ((const float4*)g)[t];
  float4 bb = ((const float4*)b)[t];
  float o0 = (v.x - mu) * rstd * gg.x + bb.x;
  float o1 = (v.y - mu) * rstd * gg.y + bb.y;
  float o2 = (v.z - mu) * rstd * gg.z + bb.z;
  float o3 = (v.w - mu) * rstd * gg.w + bb.w;
  if (f32out) {
    float* op = x0 + (size_t)(blk - 8192) * 1024 + t * 4;
    op[0] = o0; op[1] = o1; op[2] = o2; op[3] = o3;
  } else {
    unsigned short* op = hbf + (size_t)blk * 1024 + t * 4;
    op[0] = f2bf(o0); op[1] = f2bf(o1); op[2] = f2bf(o2); op[3] = f2bf(o3);
  }
}

// ---------------- generic LN (8 rows) for LN2
__global__ __launch_bounds__(256) void ln_kernel(
    const float* __restrict__ x, long in_stride, const float* __restrict__ g,
    const float* __restrict__ b, float* __restrict__ out) {
  const float* xr = x + (size_t)blockIdx.x * in_stride;
  int t = threadIdx.x;
  float4 v = ((const float4*)xr)[t];
  float s  = v.x + v.y + v.z + v.w;
  float sq = v.x * v.x + v.y * v.y + v.z * v.z + v.w * v.w;
#pragma unroll
  for (int o = 32; o; o >>= 1) { s += __shfl_down(s, o); sq += __shfl_down(sq, o); }
  __shared__ float rs_[4], rq_[4], stat[2];
  int w = t >> 6, l = t & 63;
  if (l == 0) { rs_[w] = s; rq_[w] = sq; }
  __syncthreads();
  if (t == 0) {
    float S = rs_[0] + rs_[1] + rs_[2] + rs_[3];
    float Q = rq_[0] + rq_[1] + rq_[2] + rq_[3];
    float mu = S * (1.0f / 1024.0f);
    float var = Q * (1.0f / 1024.0f) - mu * mu;
    stat[0] = mu; stat[1] = rsqrtf(var + 1e-5f);
  }
  __syncthreads();
  float mu = stat[0], rstd = stat[1];
  float4 gg = ((const float4*)g)[t];
  float4 bb = ((const float4*)b)[t];
  float* op = out + (size_t)blockIdx.x * 1024 + t * 4;
  op[0] = (v.x - mu) * rstd * gg.x + bb.x;
  op[1] = (v.y - mu) * rstd * gg.y + bb.y;
  op[2] = (v.z - mu) * rstd * gg.z + bb.z;
  op[3] = (v.w - mu) * rstd * gg.w + bb.w;
}

// ---------------- skinny GEMM: Y[8][N] = f(X[8][K] @ W[N][K]^T + bias [+ LoRA] [+resid])
// LoRA (when Amat!=null, K must be 1024): T[m][r] = X[m].Amat[r];  Y += 2*Bmat[n][r]*T[m][r]
// X row m at: X + head*xhs + m*xrs, head = first-col/64 (for per-head pv input).
template <int CPW>
__global__ __launch_bounds__(256) void skinny_gemm(
    const float* __restrict__ X, long xrs, long xhs,
    const float* __restrict__ W, const float* __restrict__ bias,
    const float* __restrict__ Amat, const float* __restrict__ Bmat,
    const float* __restrict__ resid, long rstride,
    float* __restrict__ Y, int N, int K, int do_gelu) {
  __shared__ float sX[8][1024];
  __shared__ float sT[8][8][4];
  __shared__ float T[8][8];
  int t = threadIdx.x, w = t >> 6, l = t & 63;
  int bcol = blockIdx.x * (4 * CPW);
  int col0 = bcol + w * CPW;
  int head = bcol >> 6;
  const float* Xb = X + (size_t)head * xhs;
  float acc[CPW][8];
#pragma unroll
  for (int c = 0; c < CPW; ++c)
#pragma unroll
    for (int m = 0; m < 8; ++m) acc[c][m] = 0.f;
  for (int kc = 0; kc < K; kc += 1024) {
    for (int i = t; i < 2048; i += 256) {
      int m = i >> 8, p = i & 255;
      ((float4*)sX[m])[p] = *(const float4*)(Xb + (size_t)m * xrs + kc + p * 4);
    }
    __syncthreads();
    if (Amat && kc == 0) {
      int m = t >> 5, r = (t >> 2) & 7, q = t & 3;
      float s = 0.f;
      const float* ar = Amat + r * 1024 + q * 256;
      const float* xr = &sX[m][q * 256];
      for (int j = 0; j < 256; j += 4)
        s += xr[j] * ar[j] + xr[j+1] * ar[j+1] + xr[j+2] * ar[j+2] + xr[j+3] * ar[j+3];
      sT[m][r][q] = s;
      __syncthreads();
      if (t < 64) {
        int mm = t >> 3, rr = t & 7;
        T[mm][rr] = sT[mm][rr][0] + sT[mm][rr][1] + sT[mm][rr][2] + sT[mm][rr][3];
      }
      __syncthreads();
    }
#pragma unroll
    for (int i = 0; i < 4; ++i) {
      int k = i * 256 + l * 4;
      float4 xv[8];
#pragma unroll
      for (int m = 0; m < 8; ++m) xv[m] = *(const float4*)&sX[m][k];
#pragma unroll
      for (int c = 0; c < CPW; ++c) {
        float4 wv = *(const float4*)(W + (size_t)(col0 + c) * K + kc + k);
#pragma unroll
        for (int m = 0; m < 8; ++m)
          acc[c][m] += wv.x * xv[m].x + wv.y * xv[m].y + wv.z * xv[m].z + wv.w * xv[m].w;
      }
    }
    __syncthreads();
  }
#pragma unroll
  for (int c = 0; c < CPW; ++c)
#pragma unroll
    for (int m = 0; m < 8; ++m) {
      float v = acc[c][m];
#pragma unroll
      for (int o = 32; o; o >>= 1) v += __shfl_down(v, o);
      acc[c][m] = v;
    }
  if (l == 0) {
#pragma unroll
    for (int c = 0; c < CPW; ++c) {
      int col = col0 + c;
      float bv = bias ? bias[col] : 0.f;
      float lb[8];
      if (Amat) {
#pragma unroll
        for (int r = 0; r < 8; ++r) lb[r] = Bmat[col * 8 + r];
      }
#pragma unroll
      for (int m = 0; m < 8; ++m) {
        float v = acc[c][m] + bv;
        if (Amat) {
#pragma unroll
          for (int r = 0; r < 8; ++r) v += 2.0f * lb[r] * T[m][r];
        }
        if (do_gelu) v = gelu_exact(v);
        if (resid) v += resid[(size_t)m * rstride + col];
        Y[(size_t)m * N + col] = v;
      }
    }
  }
}

// ---------------- pullback: qh[h][b][c] = sum_{d<64} q0[b][h*64+d]*WkE[h*64+d][c]
// WkE applied exactly: Wk + 2*Bk@Ak via in-kernel t_k (dot-64, cheap).
__global__ __launch_bounds__(256) void pullback_kernel(
    const float* __restrict__ q0, const float* __restrict__ Wk,
    const float* __restrict__ Ak, const float* __restrict__ Bk,
    float* __restrict__ qh) {
  int head = blockIdx.x >> 2, cchunk = blockIdx.x & 3;
  int t = threadIdx.x;
  int c = cchunk * 256 + t;
  __shared__ float sq[8][64];
  __shared__ float sT[8][8][4];
  __shared__ float T[8][8];
  if (t < 512) { int b = t >> 6, d = t & 63; sq[b][d] = q0[b * 1024 + head * 64 + d]; }
  __syncthreads();
  {
    int b = t >> 5, r = (t >> 2) & 7, q = t & 3;
    float s = 0.f;
#pragma unroll
    for (int j = 0; j < 16; ++j) {
      int d = q * 16 + j;
      s += sq[b][d] * Bk[(head * 64 + d) * 8 + r];
    }
    sT[b][r][q] = s;
  }
  __syncthreads();
  if (t < 64) {
    int b = t >> 3, r = t & 7;
    T[b][r] = sT[b][r][0] + sT[b][r][1] + sT[b][r][2] + sT[b][r][3];
  }
  __syncthreads();
  float acc[8] = {0.f, 0.f, 0.f, 0.f, 0.f, 0.f, 0.f, 0.f};
  for (int d = 0; d < 64; ++d) {
    float wv = Wk[(size_t)(head * 64 + d) * 1024 + c];
#pragma unroll
    for (int b = 0; b < 8; ++b) acc[b] += sq[b][d] * wv;
  }
  float av[8];
#pragma unroll
  for (int r = 0; r < 8; ++r) av[r] = Ak[r * 1024 + c];
#pragma unroll
  for (int b = 0; b < 8; ++b) {
    float v = acc[b];
#pragma unroll
    for (int r = 0; r < 8; ++r) v += 2.0f * T[b][r] * av[r];
    qh[(size_t)(head * 8 + b) * 1024 + c] = v;
  }
}

// ---------------- scores: sraw[h*8+b][k] = qh[h][b] . h_bf[b,k,:] * 0.125
// 256 blocks: (khalf, h, b); wave per k, 16 c per lane (hoisted qh in regs).
__global__ __launch_bounds__(256) void scores_kernel(
    const float* __restrict__ qh, const unsigned short* __restrict__ hbf,
    float* __restrict__ sraw) {
  int blk = blockIdx.x;
  int b = blk & 7, hh = (blk >> 3) & 15, khalf = blk >> 7;
  int t = threadIdx.x, w = t >> 6, l = t & 63;
  __shared__ float sq[1024];
  for (int i = t; i < 1024; i += 256) sq[i] = qh[(size_t)(hh * 8 + b) * 1024 + i];
  __syncthreads();
  float qv[16];
#pragma unroll
  for (int j = 0; j < 16; ++j) qv[j] = sq[l * 16 + j];
  const unsigned short* hb = hbf + (size_t)b * 1048576;
  float* srow = sraw + (size_t)(hh * 8 + b) * 1024;
  int kbase = khalf * 512 + w;
  for (int i = 0; i < 128; ++i) {
    int k = kbase + 4 * i;
    const uint4* hp = (const uint4*)(hb + (size_t)k * 1024 + l * 16);
    uint4 u0 = hp[0];
    uint4 u1 = hp[1];
    float s = qv[0] * blo(u0.x) + qv[1] * bhi(u0.x)
            + qv[2] * blo(u0.y) + qv[3] * bhi(u0.y)
            + qv[4] * blo(u0.z) + qv[5] * bhi(u0.z)
            + qv[6] * blo(u0.w) + qv[7] * bhi(u0.w)
            + qv[8] * blo(u1.x) + qv[9] * bhi(u1.x)
            + qv[10] * blo(u1.y) + qv[11] * bhi(u1.y)
            + qv[12] * blo(u1.z) + qv[13] * bhi(u1.z)
            + qv[14] * blo(u1.w) + qv[15] * bhi(u1.w);
#pragma unroll
    for (int o = 1; o < 64; o <<= 1) s += __shfl_xor(s, o);
    if (l == 0) srow[k] = s * 0.125f;
  }
}

// ---------------- softmax + PV: pv[h][b][c] = sum_k softmax(sraw)[k] * h_bf[b,k,c]
// 256 blocks: (chalf, h, b); thread owns 2 consecutive c (one bf16 dword per k).
__global__ __launch_bounds__(256) void pv_kernel(
    const float* __restrict__ sraw, const unsigned short* __restrict__ hbf,
    float* __restrict__ pv) {
  int blk = blockIdx.x;
  int b = blk & 7, hh = (blk >> 3) & 15, chalf = blk >> 7;
  int t = threadIdx.x, w = t >> 6, l = t & 63;
  __shared__ float sp[1024];
  __shared__ float red[8], stat[2];
  const float* srow = sraw + (size_t)(hh * 8 + b) * 1024;
  float4 s4 = ((const float4*)srow)[t];
  float m4 = fmaxf(fmaxf(s4.x, s4.y), fmaxf(s4.z, s4.w));
#pragma unroll
  for (int o = 32; o; o >>= 1) m4 = fmaxf(m4, __shfl_down(m4, o));
  if (l == 0) red[w] = m4;
  __syncthreads();
  if (t == 0) stat[0] = fmaxf(fmaxf(red[0], red[1]), fmaxf(red[2], red[3]));
  __syncthreads();
  float gmax = stat[0];
  float e0 = expf(s4.x - gmax), e1 = expf(s4.y - gmax);
  float e2 = expf(s4.z - gmax), e3 = expf(s4.w - gmax);
  sp[t * 4] = e0; sp[t * 4 + 1] = e1; sp[t * 4 + 2] = e2; sp[t * 4 + 3] = e3;
  float lsum = e0 + e1 + e2 + e3;
#pragma unroll
  for (int o = 32; o; o >>= 1) lsum += __shfl_down(lsum, o);
  if (l == 0) red[4 + w] = lsum;
  __syncthreads();
  if (t == 0) stat[1] = 1.0f / (red[4] + red[5] + red[6] + red[7]);
  __syncthreads();
  float inv = stat[1];
  int c0 = chalf * 512 + t * 2;
  const unsigned short* hp = hbf + (size_t)b * 1048576 + c0;
  float a0 = 0.f, a1 = 0.f;
  for (int k = 0; k < 1024; ++k) {
    unsigned int u = *(const unsigned int*)(hp + (size_t)k * 1024);
    float pk = sp[k];
    a0 += pk * blo(u);
    a1 += pk * bhi(u);
  }
  float* op = pv + (size_t)(hh * 8 + b) * 1024 + c0;
  op[0] = a0 * inv;
  op[1] = a1 * inv;
}

// ---------------- classifier head
__global__ __launch_bounds__(256) void logits_kernel(
    const float* __restrict__ cmid, const float* __restrict__ Wc2,
    const float* __restrict__ bc2, float* __restrict__ out) {
  int t = threadIdx.x;
  int o = t >> 3, s = t & 7;
  float a = 0.f;
  if (o < 24) {
    int b = o / 3, n = o % 3;
    const float* x = cmid + b * 512 + s * 64;
    const float* w = Wc2 + n * 512 + s * 64;
#pragma unroll
    for (int k = 0; k < 64; ++k) a += x[k] * w[k];
  }
  __shared__ float part[32][8];
  part[o][s] = a;
  __syncthreads();
  if (t < 24) {
    float v = bc2[t % 3];
#pragma unroll
    for (int ss = 0; ss < 8; ++ss) v += part[t][ss];
    out[t] = v;
  }
}

extern "C" void kernel_launch(void* const* d_in, const int* in_sizes, int n_in,
                              void* d_out, int out_size, void* d_ws, size_t ws_size,
                              hipStream_t stream) {
  const float* x    = (const float*)d_in[0];
  const float* Wq   = (const float*)d_in[1];
  const float* Aq   = (const float*)d_in[2];
  const float* Bq   = (const float*)d_in[3];
  const float* Wk   = (const float*)d_in[4];
  const float* Ak   = (const float*)d_in[5];
  const float* Bk   = (const float*)d_in[6];
  const float* Wv   = (const float*)d_in[7];
  const float* Av   = (const float*)d_in[8];
  const float* Bv   = (const float*)d_in[9];
  const float* Wo   = (const float*)d_in[10];
  const float* Ao   = (const float*)d_in[11];
  const float* Bo   = (const float*)d_in[12];
  const float* ln1g = (const float*)d_in[13];
  const float* ln1b = (const float*)d_in[14];
  const float* ln2g = (const float*)d_in[15];
  const float* ln2b = (const float*)d_in[16];
  const float* W1   = (const float*)d_in[17];
  const float* b1   = (const float*)d_in[18];
  const float* W2   = (const float*)d_in[19];
  const float* b2   = (const float*)d_in[20];
  const float* Wc1  = (const float*)d_in[21];
  const float* bc1  = (const float*)d_in[22];
  const float* Wc2  = (const float*)d_in[23];
  const float* bc2  = (const float*)d_in[24];

  char* ws = (char*)d_ws;
  size_t off = 0;
  auto alloc = [&](size_t bytes) {
    void* p = ws + off;
    off += (bytes + 255) & ~(size_t)255;
    return p;
  };
  unsigned short* h_bf = (unsigned short*)alloc((size_t)8192 * 1024 * 2);
  float* qh   = (float*)alloc((size_t)128 * 1024 * 4);
  float* sraw = (float*)alloc((size_t)128 * 1024 * 4);
  float* pvb  = (float*)alloc((size_t)128 * 1024 * 4);
  float* x0   = (float*)alloc(8 * 1024 * 4);
  float* q0   = (float*)alloc(8 * 1024 * 4);
  float* ctx0 = (float*)alloc(8 * 1024 * 4);
  float* h2   = (float*)alloc(8 * 1024 * 4);
  float* hn   = (float*)alloc(8 * 1024 * 4);
  float* mid  = (float*)alloc(8 * 4096 * 4);
  float* pooled = (float*)alloc(8 * 1024 * 4);
  float* cmid = (float*)alloc(8 * 512 * 4);

  // LN1: full 8192 rows -> bf16 h; +8 blocks for s=0 rows -> fp32 x0
  ln_fused<<<8200, 256, 0, stream>>>(x, ln1g, ln1b, h_bf, x0);
  // Q projection with exact LoRA (in-kernel T)
  skinny_gemm<1><<<256, 256, 0, stream>>>(x0, 1024, 0, Wq, nullptr, Aq, Bq,
                                          nullptr, 0, q0, 1024, 1024, 0);
  // pull q0 back through WkE -> qh[h][b][1024]
  pullback_kernel<<<64, 256, 0, stream>>>(q0, Wk, Ak, Bk, qh);
  // scores over all k (reads h, bf16)
  scores_kernel<<<256, 256, 0, stream>>>(qh, h_bf, sraw);
  // softmax + PV accumulation (reads h again, L2-hot)
  pv_kernel<<<256, 256, 0, stream>>>(sraw, h_bf, pvb);
  // V projection: ctx[b][n] = pv[head(n)][b] . WvE[n]  (head-indexed X + LoRA)
  skinny_gemm<1><<<256, 256, 0, stream>>>(pvb, 1024, 8192, Wv, nullptr, Av, Bv,
                                          nullptr, 0, ctx0, 1024, 1024, 0);
  // O projection + LoRA + residual x[:,0,:]
  skinny_gemm<1><<<256, 256, 0, stream>>>(ctx0, 1024, 0, Wo, nullptr, Ao, Bo,
                                          x, 1048576, h2, 1024, 1024, 0);
  // LN2 on 8 rows
  ln_kernel<<<8, 256, 0, stream>>>(h2, 1024, ln2g, ln2b, hn);
  // FFN
  skinny_gemm<4><<<256, 256, 0, stream>>>(hn, 1024, 0, W1, b1, nullptr, nullptr,
                                          nullptr, 0, mid, 4096, 1024, 1);
  skinny_gemm<1><<<256, 256, 0, stream>>>(mid, 4096, 0, W2, b2, nullptr, nullptr,
                                          h2, 1024, pooled, 1024, 4096, 0);
  // classifier
  skinny_gemm<1><<<128, 256, 0, stream>>>(pooled, 1024, 0, Wc1, bc1, nullptr,
                                          nullptr, nullptr, 0, cmid, 512, 1024, 1);
  logits_kernel<<<1, 256, 0, stream>>>(cmid, Wc2, bc2, (float*)d_out);
}

// Round 4
// 173.310 us; speedup vs baseline: 1.2756x; 1.2756x over previous
//
#include <hip/hip_runtime.h>
#include <hip/hip_bf16.h>

// B=8, S=1024, D=1024, H=16, HD=64, R=8, SCALING=2.0, DFF=4096, DC=512, NC=3.
// Output depends only on h[:,0]. Attention at query 0 never needs K or V:
//   score[b,h,k] = sum_c qh[b,h,c] * h[b,k,c]   (qh = q0 pulled back through WkE)
//   ctx[b,n]     = sum_c pv[b,head(n),c] * WvE[n,c],  pv[b,h,c] = sum_k p[b,h,k] h[b,k,c]
// pv is computed k-chunked with row-coalesced reads and 64 independent
// accumulators per thread (fixes the 81us serial-latency pv of round 3).

typedef float f32x4 __attribute__((ext_vector_type(4)));

__device__ __forceinline__ float blo(unsigned int u) {
  union { unsigned int i; float f; } v; v.i = u << 16; return v.f;
}
__device__ __forceinline__ float bhi(unsigned int u) {
  union { unsigned int i; float f; } v; v.i = u & 0xffff0000u; return v.f;
}
__device__ __forceinline__ unsigned short f2bf(float f) {
  union { float f; unsigned int i; } v; v.f = f;
  unsigned int u = v.i;
  u += 0x7FFFu + ((u >> 16) & 1u);
  return (unsigned short)(u >> 16);
}
__device__ __forceinline__ float gelu_exact(float x) {
  return 0.5f * x * (1.0f + erff(x * 0.70710678118654752440f));
}

// ---------------- LN1 fused: blocks 0..8191 -> h bf16; blocks 8192..8199 -> x0 fp32
__global__ __launch_bounds__(256) void ln_fused(
    const float* __restrict__ x, const float* __restrict__ g,
    const float* __restrict__ b, unsigned short* __restrict__ hbf,
    float* __restrict__ x0) {
  int blk = blockIdx.x;
  int f32out = (blk >= 8192);
  const float* xr = f32out ? (x + (size_t)(blk - 8192) * 1048576)
                           : (x + (size_t)blk * 1024);
  int t = threadIdx.x;
  float4 v = ((const float4*)xr)[t];
  float s  = v.x + v.y + v.z + v.w;
  float sq = v.x * v.x + v.y * v.y + v.z * v.z + v.w * v.w;
#pragma unroll
  for (int o = 32; o; o >>= 1) { s += __shfl_down(s, o); sq += __shfl_down(sq, o); }
  __shared__ float rs_[4], rq_[4], stat[2];
  int w = t >> 6, l = t & 63;
  if (l == 0) { rs_[w] = s; rq_[w] = sq; }
  __syncthreads();
  if (t == 0) {
    float S = rs_[0] + rs_[1] + rs_[2] + rs_[3];
    float Q = rq_[0] + rq_[1] + rq_[2] + rq_[3];
    float mu = S * (1.0f / 1024.0f);
    float var = Q * (1.0f / 1024.0f) - mu * mu;
    stat[0] = mu; stat[1] = rsqrtf(var + 1e-5f);
  }
  __syncthreads();
  float mu = stat[0], rstd = stat[1];
  float4 gg = ((const float4*)g)[t];
  float4 bb = ((const float4*)b)[t];
  float o0 = (v.x - mu) * rstd * gg.x + bb.x;
  float o1 = (v.y - mu) * rstd * gg.y + bb.y;
  float o2 = (v.z - mu) * rstd * gg.z + bb.z;
  float o3 = (v.w - mu) * rstd * gg.w + bb.w;
  if (f32out) {
    float* op = x0 + (size_t)(blk - 8192) * 1024 + t * 4;
    op[0] = o0; op[1] = o1; op[2] = o2; op[3] = o3;
  } else {
    unsigned short* op = hbf + (size_t)blk * 1024 + t * 4;
    op[0] = f2bf(o0); op[1] = f2bf(o1); op[2] = f2bf(o2); op[3] = f2bf(o3);
  }
}

// ---------------- generic LN (8 rows) for LN2
__global__ __launch_bounds__(256) void ln_kernel(
    const float* __restrict__ x, long in_stride, const float* __restrict__ g,
    const float* __restrict__ b, float* __restrict__ out) {
  const float* xr = x + (size_t)blockIdx.x * in_stride;
  int t = threadIdx.x;
  float4 v = ((const float4*)xr)[t];
  float s  = v.x + v.y + v.z + v.w;
  float sq = v.x * v.x + v.y * v.y + v.z * v.z + v.w * v.w;
#pragma unroll
  for (int o = 32; o; o >>= 1) { s += __shfl_down(s, o); sq += __shfl_down(sq, o); }
  __shared__ float rs_[4], rq_[4], stat[2];
  int w = t >> 6, l = t & 63;
  if (l == 0) { rs_[w] = s; rq_[w] = sq; }
  __syncthreads();
  if (t == 0) {
    float S = rs_[0] + rs_[1] + rs_[2] + rs_[3];
    float Q = rq_[0] + rq_[1] + rq_[2] + rq_[3];
    float mu = S * (1.0f / 1024.0f);
    float var = Q * (1.0f / 1024.0f) - mu * mu;
    stat[0] = mu; stat[1] = rsqrtf(var + 1e-5f);
  }
  __syncthreads();
  float mu = stat[0], rstd = stat[1];
  float4 gg = ((const float4*)g)[t];
  float4 bb = ((const float4*)b)[t];
  float* op = out + (size_t)blockIdx.x * 1024 + t * 4;
  op[0] = (v.x - mu) * rstd * gg.x + bb.x;
  op[1] = (v.y - mu) * rstd * gg.y + bb.y;
  op[2] = (v.z - mu) * rstd * gg.z + bb.z;
  op[3] = (v.w - mu) * rstd * gg.w + bb.w;
}

// ---------------- skinny GEMM: Y[8][N] = f(X[8][K] @ W[N][K]^T + bias [+LoRA] [+resid])
template <int CPW>
__global__ __launch_bounds__(256) void skinny_gemm(
    const float* __restrict__ X, long xrs, long xhs,
    const float* __restrict__ W, const float* __restrict__ bias,
    const float* __restrict__ Amat, const float* __restrict__ Bmat,
    const float* __restrict__ resid, long rstride,
    float* __restrict__ Y, int N, int K, int do_gelu) {
  __shared__ float sX[8][1024];
  __shared__ float sT[8][8][4];
  __shared__ float T[8][8];
  int t = threadIdx.x, w = t >> 6, l = t & 63;
  int bcol = blockIdx.x * (4 * CPW);
  int col0 = bcol + w * CPW;
  int head = bcol >> 6;
  const float* Xb = X + (size_t)head * xhs;
  float acc[CPW][8];
#pragma unroll
  for (int c = 0; c < CPW; ++c)
#pragma unroll
    for (int m = 0; m < 8; ++m) acc[c][m] = 0.f;
  for (int kc = 0; kc < K; kc += 1024) {
    for (int i = t; i < 2048; i += 256) {
      int m = i >> 8, p = i & 255;
      ((float4*)sX[m])[p] = *(const float4*)(Xb + (size_t)m * xrs + kc + p * 4);
    }
    __syncthreads();
    if (Amat && kc == 0) {
      int m = t >> 5, r = (t >> 2) & 7, q = t & 3;
      float s = 0.f;
      const float* ar = Amat + r * 1024 + q * 256;
      const float* xr = &sX[m][q * 256];
      for (int j = 0; j < 256; j += 4)
        s += xr[j] * ar[j] + xr[j+1] * ar[j+1] + xr[j+2] * ar[j+2] + xr[j+3] * ar[j+3];
      sT[m][r][q] = s;
      __syncthreads();
      if (t < 64) {
        int mm = t >> 3, rr = t & 7;
        T[mm][rr] = sT[mm][rr][0] + sT[mm][rr][1] + sT[mm][rr][2] + sT[mm][rr][3];
      }
      __syncthreads();
    }
#pragma unroll
    for (int i = 0; i < 4; ++i) {
      int k = i * 256 + l * 4;
      float4 xv[8];
#pragma unroll
      for (int m = 0; m < 8; ++m) xv[m] = *(const float4*)&sX[m][k];
#pragma unroll
      for (int c = 0; c < CPW; ++c) {
        float4 wv = *(const float4*)(W + (size_t)(col0 + c) * K + kc + k);
#pragma unroll
        for (int m = 0; m < 8; ++m)
          acc[c][m] += wv.x * xv[m].x + wv.y * xv[m].y + wv.z * xv[m].z + wv.w * xv[m].w;
      }
    }
    __syncthreads();
  }
#pragma unroll
  for (int c = 0; c < CPW; ++c)
#pragma unroll
    for (int m = 0; m < 8; ++m) {
      float v = acc[c][m];
#pragma unroll
      for (int o = 32; o; o >>= 1) v += __shfl_down(v, o);
      acc[c][m] = v;
    }
  if (l == 0) {
#pragma unroll
    for (int c = 0; c < CPW; ++c) {
      int col = col0 + c;
      float bv = bias ? bias[col] : 0.f;
      float lb[8];
      if (Amat) {
#pragma unroll
        for (int r = 0; r < 8; ++r) lb[r] = Bmat[col * 8 + r];
      }
#pragma unroll
      for (int m = 0; m < 8; ++m) {
        float v = acc[c][m] + bv;
        if (Amat) {
#pragma unroll
          for (int r = 0; r < 8; ++r) v += 2.0f * lb[r] * T[m][r];
        }
        if (do_gelu) v = gelu_exact(v);
        if (resid) v += resid[(size_t)m * rstride + col];
        Y[(size_t)m * N + col] = v;
      }
    }
  }
}

// ---------------- pullback: qh[h][b][c] = sum_{d<64} q0[b][h*64+d]*WkE[h*64+d][c]
__global__ __launch_bounds__(256) void pullback_kernel(
    const float* __restrict__ q0, const float* __restrict__ Wk,
    const float* __restrict__ Ak, const float* __restrict__ Bk,
    float* __restrict__ qh) {
  int head = blockIdx.x >> 2, cchunk = blockIdx.x & 3;
  int t = threadIdx.x;
  int c = cchunk * 256 + t;
  __shared__ float sq[8][64];
  __shared__ float sT[8][8][4];
  __shared__ float T[8][8];
  if (t < 512) { int b = t >> 6, d = t & 63; sq[b][d] = q0[b * 1024 + head * 64 + d]; }
  __syncthreads();
  {
    int b = t >> 5, r = (t >> 2) & 7, q = t & 3;
    float s = 0.f;
#pragma unroll
    for (int j = 0; j < 16; ++j) {
      int d = q * 16 + j;
      s += sq[b][d] * Bk[(head * 64 + d) * 8 + r];
    }
    sT[b][r][q] = s;
  }
  __syncthreads();
  if (t < 64) {
    int b = t >> 3, r = t & 7;
    T[b][r] = sT[b][r][0] + sT[b][r][1] + sT[b][r][2] + sT[b][r][3];
  }
  __syncthreads();
  float acc[8] = {0.f, 0.f, 0.f, 0.f, 0.f, 0.f, 0.f, 0.f};
#pragma unroll 4
  for (int d = 0; d < 64; ++d) {
    float wv = Wk[(size_t)(head * 64 + d) * 1024 + c];
#pragma unroll
    for (int b = 0; b < 8; ++b) acc[b] += sq[b][d] * wv;
  }
  float av[8];
#pragma unroll
  for (int r = 0; r < 8; ++r) av[r] = Ak[r * 1024 + c];
#pragma unroll
  for (int b = 0; b < 8; ++b) {
    float v = acc[b];
#pragma unroll
    for (int r = 0; r < 8; ++r) v += 2.0f * T[b][r] * av[r];
    qh[(size_t)(head * 8 + b) * 1024 + c] = v;
  }
}

// ---------------- scores: sraw[h*8+b][k] = qh[h][b] . h_bf[b,k,:] * 0.125
// 512 blocks: (kquarter, h, b); wave per k, 16 c per lane.
__global__ __launch_bounds__(256) void scores_kernel(
    const float* __restrict__ qh, const unsigned short* __restrict__ hbf,
    float* __restrict__ sraw) {
  int blk = blockIdx.x;
  int b = blk & 7, hh = (blk >> 3) & 15, kq = blk >> 7;
  int t = threadIdx.x, w = t >> 6, l = t & 63;
  __shared__ float sq[1024];
  for (int i = t; i < 1024; i += 256) sq[i] = qh[(size_t)(hh * 8 + b) * 1024 + i];
  __syncthreads();
  float qv[16];
#pragma unroll
  for (int j = 0; j < 16; ++j) qv[j] = sq[l * 16 + j];
  const unsigned short* hb = hbf + (size_t)b * 1048576;
  float* srow = sraw + (size_t)(hh * 8 + b) * 1024;
  int kbase = kq * 256 + w;
  for (int i = 0; i < 64; ++i) {
    int k = kbase + 4 * i;
    const uint4* hp = (const uint4*)(hb + (size_t)k * 1024 + l * 16);
    uint4 u0 = hp[0];
    uint4 u1 = hp[1];
    float s = qv[0] * blo(u0.x) + qv[1] * bhi(u0.x)
            + qv[2] * blo(u0.y) + qv[3] * bhi(u0.y)
            + qv[4] * blo(u0.z) + qv[5] * bhi(u0.z)
            + qv[6] * blo(u0.w) + qv[7] * bhi(u0.w)
            + qv[8] * blo(u1.x) + qv[9] * bhi(u1.x)
            + qv[10] * blo(u1.y) + qv[11] * bhi(u1.y)
            + qv[12] * blo(u1.z) + qv[13] * bhi(u1.z)
            + qv[14] * blo(u1.w) + qv[15] * bhi(u1.w);
#pragma unroll
    for (int o = 1; o < 64; o <<= 1) s += __shfl_xor(s, o);
    if (l == 0) srow[k] = s * 0.125f;
  }
}

// ---------------- softmax over each of 128 rows of sraw -> normalized p (fp32)
__global__ __launch_bounds__(256) void softmax_kernel(
    const float* __restrict__ sraw, float* __restrict__ p) {
  int row = blockIdx.x;
  int t = threadIdx.x, w = t >> 6, l = t & 63;
  __shared__ float red[8], stat[2];
  float4 s4 = ((const float4*)(sraw + (size_t)row * 1024))[t];
  float m4 = fmaxf(fmaxf(s4.x, s4.y), fmaxf(s4.z, s4.w));
#pragma unroll
  for (int o = 32; o; o >>= 1) m4 = fmaxf(m4, __shfl_down(m4, o));
  if (l == 0) red[w] = m4;
  __syncthreads();
  if (t == 0) stat[0] = fmaxf(fmaxf(red[0], red[1]), fmaxf(red[2], red[3]));
  __syncthreads();
  float gmax = stat[0];
  float e0 = expf(s4.x - gmax), e1 = expf(s4.y - gmax);
  float e2 = expf(s4.z - gmax), e3 = expf(s4.w - gmax);
  float lsum = e0 + e1 + e2 + e3;
#pragma unroll
  for (int o = 32; o; o >>= 1) lsum += __shfl_down(lsum, o);
  if (l == 0) red[4 + w] = lsum;
  __syncthreads();
  if (t == 0) stat[1] = 1.0f / (red[4] + red[5] + red[6] + red[7]);
  __syncthreads();
  float inv = stat[1];
  float4 o4; o4.x = e0 * inv; o4.y = e1 * inv; o4.z = e2 * inv; o4.w = e3 * inv;
  ((float4*)(p + (size_t)row * 1024))[t] = o4;
}

// ---------------- pv partial: block (b, kc of 32 k): all 16 heads, rows coalesced.
// partial[(kc*8+b)][h][c] = sum_{k in chunk} p[h*8+b][k] * h_bf[b][k][c]
__global__ __launch_bounds__(256) void pv_partial(
    const float* __restrict__ p, const unsigned short* __restrict__ hbf,
    float* __restrict__ partial) {
  int blk = blockIdx.x;            // 256 = kc*8 + b
  int b = blk & 7, kc = blk >> 3;
  int t = threadIdx.x;
  __shared__ float sp[32][16];
  for (int i = t; i < 512; i += 256) {
    int h = i >> 5, kk = i & 31;
    sp[kk][h] = p[(size_t)(h * 8 + b) * 1024 + kc * 32 + kk];
  }
  __syncthreads();
  int c0 = t * 4;
  const unsigned short* hp = hbf + (size_t)b * 1048576 + (size_t)kc * 32 * 1024 + c0;
  float4 acc[16];
#pragma unroll
  for (int h = 0; h < 16; ++h) acc[h] = (float4){0.f, 0.f, 0.f, 0.f};
#pragma unroll 4
  for (int kk = 0; kk < 32; ++kk) {
    uint2 u = *(const uint2*)(hp + (size_t)kk * 1024);
    float h0 = blo(u.x), h1 = bhi(u.x), h2 = blo(u.y), h3 = bhi(u.y);
    const float4* pr = (const float4*)sp[kk];
    float4 p0 = pr[0], p1 = pr[1], p2 = pr[2], p3 = pr[3];
    float pk[16] = {p0.x, p0.y, p0.z, p0.w, p1.x, p1.y, p1.z, p1.w,
                    p2.x, p2.y, p2.z, p2.w, p3.x, p3.y, p3.z, p3.w};
#pragma unroll
    for (int h = 0; h < 16; ++h) {
      acc[h].x += pk[h] * h0;
      acc[h].y += pk[h] * h1;
      acc[h].z += pk[h] * h2;
      acc[h].w += pk[h] * h3;
    }
  }
  float* op = partial + ((size_t)blk * 16) * 1024 + c0;
#pragma unroll
  for (int h = 0; h < 16; ++h)
    *(float4*)(op + (size_t)h * 1024) = acc[h];
}

// ---------------- pv combine: pv[(h*8+b)][c] = sum_kc partial[(kc*8+b)][h][c]
__global__ __launch_bounds__(256) void pv_combine(
    const float* __restrict__ partial, float* __restrict__ pv) {
  int blk = blockIdx.x;            // 128 = h*8 + b
  int h = blk >> 3, b = blk & 7;
  int c0 = threadIdx.x * 4;
  float4 a = (float4){0.f, 0.f, 0.f, 0.f};
#pragma unroll 8
  for (int kc = 0; kc < 32; ++kc) {
    float4 v = *(const float4*)(partial + ((size_t)(kc * 8 + b) * 16 + h) * 1024 + c0);
    a.x += v.x; a.y += v.y; a.z += v.z; a.w += v.w;
  }
  *(float4*)(pv + (size_t)(h * 8 + b) * 1024 + c0) = a;
}

// ---------------- classifier head
__global__ __launch_bounds__(256) void logits_kernel(
    const float* __restrict__ cmid, const float* __restrict__ Wc2,
    const float* __restrict__ bc2, float* __restrict__ out) {
  int t = threadIdx.x;
  int o = t >> 3, s = t & 7;
  float a = 0.f;
  if (o < 24) {
    int b = o / 3, n = o % 3;
    const float* x = cmid + b * 512 + s * 64;
    const float* w = Wc2 + n * 512 + s * 64;
#pragma unroll
    for (int k = 0; k < 64; ++k) a += x[k] * w[k];
  }
  __shared__ float part[32][8];
  part[o][s] = a;
  __syncthreads();
  if (t < 24) {
    float v = bc2[t % 3];
#pragma unroll
    for (int ss = 0; ss < 8; ++ss) v += part[t][ss];
    out[t] = v;
  }
}

extern "C" void kernel_launch(void* const* d_in, const int* in_sizes, int n_in,
                              void* d_out, int out_size, void* d_ws, size_t ws_size,
                              hipStream_t stream) {
  const float* x    = (const float*)d_in[0];
  const float* Wq   = (const float*)d_in[1];
  const float* Aq   = (const float*)d_in[2];
  const float* Bq   = (const float*)d_in[3];
  const float* Wk   = (const float*)d_in[4];
  const float* Ak   = (const float*)d_in[5];
  const float* Bk   = (const float*)d_in[6];
  const float* Wv   = (const float*)d_in[7];
  const float* Av   = (const float*)d_in[8];
  const float* Bv   = (const float*)d_in[9];
  const float* Wo   = (const float*)d_in[10];
  const float* Ao   = (const float*)d_in[11];
  const float* Bo   = (const float*)d_in[12];
  const float* ln1g = (const float*)d_in[13];
  const float* ln1b = (const float*)d_in[14];
  const float* ln2g = (const float*)d_in[15];
  const float* ln2b = (const float*)d_in[16];
  const float* W1   = (const float*)d_in[17];
  const float* b1   = (const float*)d_in[18];
  const float* W2   = (const float*)d_in[19];
  const float* b2   = (const float*)d_in[20];
  const float* Wc1  = (const float*)d_in[21];
  const float* bc1  = (const float*)d_in[22];
  const float* Wc2  = (const float*)d_in[23];
  const float* bc2  = (const float*)d_in[24];

  char* ws = (char*)d_ws;
  size_t off = 0;
  auto alloc = [&](size_t bytes) {
    void* p = ws + off;
    off += (bytes + 255) & ~(size_t)255;
    return p;
  };
  unsigned short* h_bf = (unsigned short*)alloc((size_t)8192 * 1024 * 2);
  float* qh      = (float*)alloc((size_t)128 * 1024 * 4);
  float* sraw    = (float*)alloc((size_t)128 * 1024 * 4);
  float* pnorm   = (float*)alloc((size_t)128 * 1024 * 4);
  float* partial = (float*)alloc((size_t)256 * 16 * 1024 * 4);
  float* pvb     = (float*)alloc((size_t)128 * 1024 * 4);
  float* x0   = (float*)alloc(8 * 1024 * 4);
  float* q0   = (float*)alloc(8 * 1024 * 4);
  float* ctx0 = (float*)alloc(8 * 1024 * 4);
  float* h2   = (float*)alloc(8 * 1024 * 4);
  float* hn   = (float*)alloc(8 * 1024 * 4);
  float* mid  = (float*)alloc(8 * 4096 * 4);
  float* pooled = (float*)alloc(8 * 1024 * 4);
  float* cmid = (float*)alloc(8 * 512 * 4);

  // LN1: full 8192 rows -> bf16 h; +8 blocks for s=0 rows -> fp32 x0
  ln_fused<<<8200, 256, 0, stream>>>(x, ln1g, ln1b, h_bf, x0);
  // Q projection with exact LoRA
  skinny_gemm<1><<<256, 256, 0, stream>>>(x0, 1024, 0, Wq, nullptr, Aq, Bq,
                                          nullptr, 0, q0, 1024, 1024, 0);
  // pull q0 back through WkE -> qh[h][b][1024]
  pullback_kernel<<<64, 256, 0, stream>>>(q0, Wk, Ak, Bk, qh);
  // scores over all k
  scores_kernel<<<512, 256, 0, stream>>>(qh, h_bf, sraw);
  // softmax -> normalized probs
  softmax_kernel<<<128, 256, 0, stream>>>(sraw, pnorm);
  // pv: k-chunked partials + combine
  pv_partial<<<256, 256, 0, stream>>>(pnorm, h_bf, partial);
  pv_combine<<<128, 256, 0, stream>>>(partial, pvb);
  // V projection: ctx[b][n] = pv[head(n)][b] . WvE[n]
  skinny_gemm<1><<<256, 256, 0, stream>>>(pvb, 1024, 8192, Wv, nullptr, Av, Bv,
                                          nullptr, 0, ctx0, 1024, 1024, 0);
  // O projection + LoRA + residual x[:,0,:]
  skinny_gemm<1><<<256, 256, 0, stream>>>(ctx0, 1024, 0, Wo, nullptr, Ao, Bo,
                                          x, 1048576, h2, 1024, 1024, 0);
  // LN2 on 8 rows
  ln_kernel<<<8, 256, 0, stream>>>(h2, 1024, ln2g, ln2b, hn);
  // FFN
  skinny_gemm<4><<<256, 256, 0, stream>>>(hn, 1024, 0, W1, b1, nullptr, nullptr,
                                          nullptr, 0, mid, 4096, 1024, 1);
  skinny_gemm<1><<<256, 256, 0, stream>>>(mid, 4096, 0, W2, b2, nullptr, nullptr,
                                          h2, 1024, pooled, 1024, 4096, 0);
  // classifier
  skinny_gemm<1><<<128, 256, 0, stream>>>(pooled, 1024, 0, Wc1, bc1, nullptr,
                                          nullptr, nullptr, 0, cmid, 512, 1024, 1);
  logits_kernel<<<1, 256, 0, stream>>>(cmid, Wc2, bc2, (float*)d_out);
}